// Round 13
// baseline (298.297 us; speedup 1.0000x reference)
//
#include <hip/hip_runtime.h>

#define B_ 8
#define C_ 128
#define N_ 4096
#define SCALE 0.08838834764831845f   // 1/sqrt(128)
#define NBLK 512u                    // grid size == exact 2-blocks/CU capacity

typedef __attribute__((ext_vector_type(8))) short short8;   // 8 bf16
typedef __attribute__((ext_vector_type(4))) short short4v;  // 4 bf16
typedef __attribute__((ext_vector_type(4))) float f32x4;    // MFMA C/D

// RNE fp32->bf16, 1 VALU inst (v_cvt_pk_bf16_f32, low half).
__device__ inline unsigned short f2b(float f) {
    unsigned int u;
    asm("v_cvt_pk_bf16_f32 %0, %1, %2" : "=v"(u) : "v"(f), "v"(f));
    return (unsigned short)u;
}

// async global->LDS, 16B per lane (m97 staging path).
__device__ inline void gld_lds16(const void* g, void* l) {
    __builtin_amdgcn_global_load_lds(
        (const __attribute__((address_space(1))) unsigned int*)g,
        (__attribute__((address_space(3))) unsigned int*)l, 16, 0, 0);
}

// ---------------------------------------------------------------------------
// R13: fused kernel (R12 phases, byte-identical) with a SOFTWARE grid
// barrier instead of hipLaunchCooperativeKernel. R12's absmax 5.125 ==
// max|ref| == "output never written": the cooperative launch failed under
// the harness's stream/graph capture (return code unchecked). A plain
// launch + atomic-counter barrier is capture-safe by construction.
// Deadlock-safety (all 512 blocks MUST be co-resident): LDS 54.0KB -> 2
// blocks/CU; VGPR<=128 (launch_bounds(512,4)) -> 16 waves/CU <= 32; grid
// 512 = 256 CU x 2 exactly. Counter is memset to 0 each replay (memset
// node in the captured graph). Cross-XCD data coherence: release
// __threadfence (L2 writeback) before arrive; ACQUIRE atomic spin +
// __threadfence (L1/L2 invalidate) after — correct for any block->XCD
// mapping (G16).
//   phase 1 (R11-proven kv): stage Xs -> v-pass -> k-pass(Obuf)
//   phase 2: q-pass on resident Xs; qf -> registers
//   grid barrier (kTs/vS visible device-wide)
//   phase 3: byte-identical R10 attn loop + epilogue.
// kTs bf16 [b][n][o'] o-blocks ^ (n&15). vS bf16 [b][o][n'] 32-key windows,
// block' ^= (o>>1)&3. XCD map b = bid&7.
// mfma_f32_16x16x32_bf16: A[m=l15][k=quad*8+j]; B[k][n=l15];
// C/D row=quad*4+r, col=l15 (end-to-end validated).
// ---------------------------------------------------------------------------
__global__ __launch_bounds__(512, 4) void fused_attn(
    const float* __restrict__ x,
    const float* __restrict__ Wq, const float* __restrict__ bq,
    const float* __restrict__ Wk, const float* __restrict__ bk,
    const float* __restrict__ Wv, const float* __restrict__ bv,
    unsigned short* __restrict__ kTs, unsigned short* __restrict__ vS,
    unsigned int* gsync,
    float* __restrict__ out)
{
    __shared__ __align__(16) union {
        struct {                          // phase 1/2: kv + q
            short Xs[64 * 128];           // 16 KB bf16 X^T, swizzled
            union {
                float Obuf[64 * 132];     // 33.8 KB k-epilogue
                short Qs[64 * 128];       // 16 KB Q^T (after k-copy done)
            } o;
        } p;                              // 49.8 KB
        struct {                          // phase 3: attn loop
            short V[2][2][4096];          // [buf][grp][128ch x 32keys]
            short Pb[2][2][2][32 * 40];   // [parity][grp][wq] 32q x 32k
        } s;                              // 52 KB
        float Ot[64 * 130];               // epilogue merge (33.3 KB)
    } sm;
    __shared__ float Ls[2][2][32];        // [g][wq][row32] row-sums
    __shared__ float linvA[64];

    const int t    = threadIdx.x;
    const int w    = t >> 6;          // 0..7
    const int g    = w >> 2;          // key-group (2048-key half)
    const int wq   = (w >> 1) & 1;    // 32-query subtile
    const int h    = w & 1;           // QK: key-half; PV: channel-half
    const int sub  = w & 3;           // staging sub-tile
    const int lane = t & 63;
    const int l15  = lane & 15;
    const int quad = lane >> 4;

    const int b  = blockIdx.x & 7;               // XCD-pinned batch
    const int n0 = (blockIdx.x >> 3) * 64;
    const long base = (long)b * C_ * N_;

    auto load_af = [&](const float* __restrict__ W, short8 (&af)[4]) {
        const int o = 16 * w + l15;
        #pragma unroll
        for (int ks = 0; ks < 4; ++ks) {
            const float4 a0 = *(const float4*)(const void*)(W + o * C_ + ks * 32 + quad * 8);
            const float4 a1 = *(const float4*)(const void*)(W + o * C_ + ks * 32 + quad * 8 + 4);
            union { unsigned int u[4]; short8 s; } pk;
            asm("v_cvt_pk_bf16_f32 %0, %1, %2" : "=v"(pk.u[0]) : "v"(a0.x), "v"(a0.y));
            asm("v_cvt_pk_bf16_f32 %0, %1, %2" : "=v"(pk.u[1]) : "v"(a0.z), "v"(a0.w));
            asm("v_cvt_pk_bf16_f32 %0, %1, %2" : "=v"(pk.u[2]) : "v"(a1.x), "v"(a1.y));
            asm("v_cvt_pk_bf16_f32 %0, %1, %2" : "=v"(pk.u[3]) : "v"(a1.z), "v"(a1.w));
            af[ks] = pk.s;
        }
    };

    auto mfma_pass = [&](const short8 (&af)[4], f32x4 (&acc)[4]) {
        #pragma unroll
        for (int nt = 0; nt < 4; ++nt) acc[nt] = (f32x4){0.f, 0.f, 0.f, 0.f};
        #pragma unroll
        for (int nt = 0; nt < 4; ++nt) {
            const int n = nt * 16 + l15;
            #pragma unroll
            for (int ks = 0; ks < 4; ++ks) {
                const short8 bx = *(const short8*)(const void*)(
                    sm.p.Xs + n * 128 + (((ks * 4 + quad) ^ l15) << 3));
                acc[nt] = __builtin_amdgcn_mfma_f32_16x16x32_bf16(af[ks], bx, acc[nt], 0, 0, 0);
            }
        }
    };

    // ================= phase 1: kv (R11-proven, bit-identical) =================
    short8 afA[4], afB[4];
    load_af(Wv, afA);

    #pragma unroll
    for (int it = 0; it < 4; ++it) {
        const int c  = (t >> 4) + it * 32;
        const int n4 = (t & 15) * 4;
        const float4 xv = *(const float4*)(const void*)(x + base + (long)c * N_ + n0 + n4);
        const int bc = c >> 3, cl = c & 7;
        sm.p.Xs[(n4 + 0) * 128 + ((bc ^ ((n4 + 0) & 15)) << 3) + cl] = (short)f2b(xv.x);
        sm.p.Xs[(n4 + 1) * 128 + ((bc ^ ((n4 + 1) & 15)) << 3) + cl] = (short)f2b(xv.y);
        sm.p.Xs[(n4 + 2) * 128 + ((bc ^ ((n4 + 2) & 15)) << 3) + cl] = (short)f2b(xv.z);
        sm.p.Xs[(n4 + 3) * 128 + ((bc ^ ((n4 + 3) & 15)) << 3) + cl] = (short)f2b(xv.w);
    }
    __syncthreads();

    { // ---- v -> vS bf16, direct swizzled store ----
        load_af(Wk, afB);                          // prefetch k weights
        f32x4 acc[4];
        mfma_pass(afA, acc);
        #pragma unroll
        for (int r = 0; r < 4; ++r) {
            const int o = 16 * w + quad * 4 + r;
            const float bb = bv[o];
            const int sw = ((o >> 1) & 3) << 3;
            #pragma unroll
            for (int nt = 0; nt < 4; ++nt) {
                const int n = nt * 16 + l15;
                const int ns = (n & 32) | ((((n >> 3) & 3) << 3) ^ sw) | (n & 7);
                vS[base + (long)o * N_ + n0 + ns] = f2b(acc[nt][r] + bb);
            }
        }
    }

    { // ---- k -> kTs bf16 [b][n][o'] via Obuf (stride 132) ----
        f32x4 acc[4];
        mfma_pass(afB, acc);
        #pragma unroll
        for (int r = 0; r < 4; ++r) {
            const int o = 16 * w + quad * 4 + r;
            const float bb = bk[o];
            #pragma unroll
            for (int nt = 0; nt < 4; ++nt) {
                const int n = nt * 16 + l15;
                sm.p.o.Obuf[n * 132 + (((o >> 3) ^ l15) << 3) + (o & 7)] = acc[nt][r] + bb;
            }
        }
        __syncthreads();
        const int n = t >> 3, oh = (t & 7) * 16;   // 8 threads cover 128 cols
        #pragma unroll
        for (int i = 0; i < 16; i += 8) {
            const float4 k0 = *(const float4*)(const void*)(sm.p.o.Obuf + n * 132 + oh + i);
            const float4 k1 = *(const float4*)(const void*)(sm.p.o.Obuf + n * 132 + oh + i + 4);
            union { unsigned int u[4]; short8 s; } pk;
            asm("v_cvt_pk_bf16_f32 %0, %1, %2" : "=v"(pk.u[0]) : "v"(k0.x), "v"(k0.y));
            asm("v_cvt_pk_bf16_f32 %0, %1, %2" : "=v"(pk.u[1]) : "v"(k0.z), "v"(k0.w));
            asm("v_cvt_pk_bf16_f32 %0, %1, %2" : "=v"(pk.u[2]) : "v"(k1.x), "v"(k1.y));
            asm("v_cvt_pk_bf16_f32 %0, %1, %2" : "=v"(pk.u[3]) : "v"(k1.z), "v"(k1.w));
            *(short8*)(void*)(kTs + base + (long)(n0 + n) * C_ + oh + i) = pk.s;
        }
    }
    __syncthreads();                  // Obuf copy-reads done -> Qs slot free

    // ================= phase 2: q on resident Xs (R10 math, verbatim) ========
    {
        short8 aq[4];
        load_af(Wq, aq);                           // same frag pattern, o=16w+l15
        f32x4 qa[4];
        #pragma unroll
        for (int nt = 0; nt < 4; ++nt) qa[nt] = (f32x4){0.f, 0.f, 0.f, 0.f};
        #pragma unroll
        for (int nt = 0; nt < 4; ++nt) {
            const int n = nt * 16 + l15;
            #pragma unroll
            for (int ks = 0; ks < 4; ++ks) {
                const short8 bx = *(const short8*)(const void*)(
                    sm.p.Xs + n * 128 + (((ks * 4 + quad) ^ l15) << 3));
                qa[nt] = __builtin_amdgcn_mfma_f32_16x16x32_bf16(aq[ks], bx, qa[nt], 0, 0, 0);
            }
        }
        const float4 bb = *(const float4*)(const void*)(bq + 16 * w + quad * 4);
        #pragma unroll
        for (int r = 0; r < 4; ++r) {
            const int oo = 16 * w + quad * 4 + r;
            const float br = r == 0 ? bb.x : r == 1 ? bb.y : r == 2 ? bb.z : bb.w;
            #pragma unroll
            for (int nt = 0; nt < 4; ++nt) {
                const int n = nt * 16 + l15;
                sm.p.o.Qs[n * 128 + (((oo >> 3) ^ (n & 15)) << 3) + (oo & 7)] =
                    (short)f2b((qa[nt][r] + br) * SCALE);
            }
        }
    }
    __syncthreads();

    short8 qf[2][4];                  // read BEFORE grid barrier (Qs dies after)
    #pragma unroll
    for (int qh = 0; qh < 2; ++qh)
        #pragma unroll
        for (int ks = 0; ks < 4; ++ks) {
            const int query = 32 * wq + qh * 16 + l15;   // local row, &15 == l15
            qf[qh][ks] = *(const short8*)(const void*)(
                sm.p.o.Qs + query * 128 + (((ks * 4 + quad) ^ l15) << 3));
        }

    // ================= software grid barrier =================
    // __syncthreads drains each wave's global stores (vmcnt 0) and covers the
    // Qs reads; t0: release fence (L2 writeback on gfx95x agent scope) ->
    // device-scope arrive -> ACQUIRE spin; then all waves fence (L1/L2
    // invalidate) so kTs/vS reads see every block's writes, any XCD mapping.
    __syncthreads();
    if (t == 0) {
        __threadfence();                                   // release: wbl2
        atomicAdd(gsync, 1u);                              // device-scope arrive
        while (__hip_atomic_load(gsync, __ATOMIC_ACQUIRE,
                                 __HIP_MEMORY_SCOPE_AGENT) < NBLK)
            __builtin_amdgcn_s_sleep(1);
    }
    __syncthreads();
    __threadfence();                                       // acquire: inv L1/L2

    // ================= phase 3: attn loop (byte-identical R10) ===============
    f32x4 acc[2][4];                  // [qh][ct]: 32q x 64c (channel-half h)
    #pragma unroll
    for (int qh = 0; qh < 2; ++qh)
        #pragma unroll
        for (int ct = 0; ct < 4; ++ct) acc[qh][ct] = (f32x4){0.f, 0.f, 0.f, 0.f};
    f32x4 accS[2];
    accS[0] = (f32x4){0.f, 0.f, 0.f, 0.f};
    accS[1] = (f32x4){0.f, 0.f, 0.f, 0.f};
    short8 ones;
    #pragma unroll
    for (int j = 0; j < 8; ++j) ones[j] = (short)0x3F80;   // bf16 1.0

    auto stageV = [&](int buf, int pair) {       // exactly 2 VMEM ops / lane
        const int mt = pair * 2 + g;
        char* lV = (char*)sm.s.V[buf][g];
        #pragma unroll
        for (int jj = 0; jj < 2; ++jj) {
            const int d  = sub * 2048 + jj * 1024;
            const int dv = d + lane * 16;
            const int c  = dv >> 6;
            gld_lds16((const char*)(vS + base + (long)c * N_ + mt * 32) + (dv & 63), lV + d);
        }
    };

    const unsigned short* kp = kTs + base + (long)((g * 32 + h * 16 + l15) * C_);
    int ko[4];
    #pragma unroll
    for (int ks = 0; ks < 4; ++ks) ko[ks] = (((ks * 4 + quad) ^ l15) << 3);
    short8 kf[4];

    stageV(0, 0);
    #pragma unroll
    for (int ks = 0; ks < 4; ++ks) kf[ks] = *(const short8*)(const void*)(kp + ko[ks]);
    kp += 64 * C_;

    for (int i = 0; i < 64; ++i) {
        // ---- QK phase (registers only): P[32q][16k(h)] ----
        f32x4 sc[2];
        sc[0] = (f32x4){0.f, 0.f, 0.f, 0.f};
        sc[1] = (f32x4){0.f, 0.f, 0.f, 0.f};
        __builtin_amdgcn_s_setprio(1);
        #pragma unroll
        for (int qh = 0; qh < 2; ++qh)
            #pragma unroll
            for (int ks = 0; ks < 4; ++ks)
                sc[qh] = __builtin_amdgcn_mfma_f32_16x16x32_bf16(qf[qh][ks], kf[ks], sc[qh], 0, 0, 0);
        __builtin_amdgcn_s_setprio(0);

        // ---- prefetch kf(i+1): regs free, ~full iteration in flight ----
        if (i < 63) {
            #pragma unroll
            for (int ks = 0; ks < 4; ++ks) kf[ks] = *(const short8*)(const void*)(kp + ko[ks]);
            kp += 64 * C_;
        }

        // ---- softmax numerator -> P (iter-parity double buffer) ----
        short* Pw = sm.s.Pb[i & 1][g][wq];
        #pragma unroll
        for (int qh = 0; qh < 2; ++qh)
            #pragma unroll
            for (int r = 0; r < 4; ++r)
                Pw[(qh * 16 + quad * 4 + r) * 40 + h * 16 + l15] = (short)f2b(__expf(sc[qh][r]));

        // ---- single sync point: V(i) staged (vmcnt: kf(i+1) stays in
        // flight), own P writes drained, then barrier ----
        if (i < 63) asm volatile("s_waitcnt vmcnt(4)" ::: "memory");
        else        asm volatile("s_waitcnt vmcnt(0)" ::: "memory");
        asm volatile("s_waitcnt lgkmcnt(0)" ::: "memory");
        __builtin_amdgcn_s_barrier();
        __builtin_amdgcn_sched_barrier(0);

        // ---- V(i+1) stage: earliest legal point ----
        if (i < 63) stageV((i + 1) & 1, i + 1);

        // ---- PV phase: channel-half h, full 32-key P ----
        const short* Vb = sm.s.V[i & 1][g];
        const short8 pf0 = *(const short8*)(const void*)(Pw + (l15) * 40 + quad * 8);
        const short8 pf1 = *(const short8*)(const void*)(Pw + (16 + l15) * 40 + quad * 8);
        __builtin_amdgcn_s_setprio(1);
        if (h == 0) {                          // row-sums once per (g,wq)
            accS[0] = __builtin_amdgcn_mfma_f32_16x16x32_bf16(pf0, ones, accS[0], 0, 0, 0);
            accS[1] = __builtin_amdgcn_mfma_f32_16x16x32_bf16(pf1, ones, accS[1], 0, 0, 0);
        }
        #pragma unroll
        for (int ct = 0; ct < 4; ++ct) {
            const int ch = h * 64 + ct * 16 + l15;
            const short8 vf = *(const short8*)(const void*)(Vb + ch * 32 + ((quad ^ ((l15 >> 1) & 3)) << 3));
            acc[0][ct] = __builtin_amdgcn_mfma_f32_16x16x32_bf16(pf0, vf, acc[0][ct], 0, 0, 0);
            acc[1][ct] = __builtin_amdgcn_mfma_f32_16x16x32_bf16(pf1, vf, acc[1][ct], 0, 0, 0);
        }
        __builtin_amdgcn_s_setprio(0);
    }

    // ---- merge epilogue: Ot = O_g0 + O_g1; l via Ls; normalize + residual ----
    if (h == 0 && l15 == 0) {
        #pragma unroll
        for (int qh = 0; qh < 2; ++qh)
            #pragma unroll
            for (int r = 0; r < 4; ++r)
                Ls[g][wq][qh * 16 + quad * 4 + r] = accS[qh][r];
    }
    __syncthreads();                  // all PV reads done before Ot overlays LDS
    if (g == 0) {
        #pragma unroll
        for (int qh = 0; qh < 2; ++qh)
            #pragma unroll
            for (int ct = 0; ct < 4; ++ct)
                #pragma unroll
                for (int r = 0; r < 4; ++r)
                    sm.Ot[(32 * wq + qh * 16 + quad * 4 + r) * 130 + h * 64 + ct * 16 + l15] = acc[qh][ct][r];
    }
    __syncthreads();
    if (g == 1) {
        #pragma unroll
        for (int qh = 0; qh < 2; ++qh)
            #pragma unroll
            for (int ct = 0; ct < 4; ++ct)
                #pragma unroll
                for (int r = 0; r < 4; ++r)
                    sm.Ot[(32 * wq + qh * 16 + quad * 4 + r) * 130 + h * 64 + ct * 16 + l15] += acc[qh][ct][r];
    } else if (h == 0 && l15 == 0) {
        #pragma unroll
        for (int qh = 0; qh < 2; ++qh)
            #pragma unroll
            for (int r = 0; r < 4; ++r) {
                const int r32 = qh * 16 + quad * 4 + r;
                linvA[32 * wq + r32] = 1.0f / fmaxf(Ls[0][wq][r32] + Ls[1][wq][r32], 1e-20f);
            }
    }
    __syncthreads();

    const int c  = t >> 2;
    const int nh = (t & 3) * 16;
    const long gb = base + (long)c * N_ + n0 + nh;
    #pragma unroll
    for (int i = 0; i < 16; i += 4) {
        const float4 xs = *(const float4*)(const void*)(x + gb + i);
        float4 rv;
        rv.x = sm.Ot[(nh + i + 0) * 130 + c] * linvA[nh + i + 0] + xs.x;
        rv.y = sm.Ot[(nh + i + 1) * 130 + c] * linvA[nh + i + 1] + xs.y;
        rv.z = sm.Ot[(nh + i + 2) * 130 + c] * linvA[nh + i + 2] + xs.z;
        rv.w = sm.Ot[(nh + i + 3) * 130 + c] * linvA[nh + i + 3] + xs.w;
        *(float4*)(void*)(out + gb + i) = rv;
    }
}

// ---------------------------------------------------------------------------
extern "C" void kernel_launch(void* const* d_in, const int* in_sizes, int n_in,
                              void* d_out, int out_size, void* d_ws, size_t ws_size,
                              hipStream_t stream) {
    const float* x  = (const float*)d_in[0];
    const float* Wq = (const float*)d_in[1];
    const float* bq = (const float*)d_in[2];
    const float* Wk = (const float*)d_in[3];
    const float* bk = (const float*)d_in[4];
    const float* Wv = (const float*)d_in[5];
    const float* bv = (const float*)d_in[6];
    float* out = (float*)d_out;

    const long BCN = (long)B_ * C_ * N_;                  // 4,194,304
    unsigned short* kTs = (unsigned short*)d_ws;          // [b][n][o'] bf16 swizzled
    unsigned short* vS  = kTs + BCN;                      // [b][o][n'] bf16 swizzled
    unsigned int* gsync = (unsigned int*)(vS + BCN);      // 4B barrier counter

    hipMemsetAsync((void*)gsync, 0, sizeof(unsigned int), stream);
    fused_attn<<<dim3(NBLK), dim3(512), 0, stream>>>(
        x, Wq, bq, Wk, bk, Wv, bv, kTs, vS, gsync, out);
}

// Round 15
// 181.914 us; speedup vs baseline: 1.6398x; 1.6398x over previous
//
#include <hip/hip_runtime.h>

#define B_ 8
#define C_ 128
#define N_ 4096
#define SCALE 0.08838834764831845f   // 1/sqrt(128)

typedef __attribute__((ext_vector_type(8))) short short8;   // 8 bf16
typedef __attribute__((ext_vector_type(4))) short short4v;  // 4 bf16
typedef __attribute__((ext_vector_type(4))) float f32x4;    // MFMA C/D

// RNE fp32->bf16, 1 VALU inst (v_cvt_pk_bf16_f32, low half).
__device__ inline unsigned short f2b(float f) {
    unsigned int u;
    asm("v_cvt_pk_bf16_f32 %0, %1, %2" : "=v"(u) : "v"(f), "v"(f));
    return (unsigned short)u;
}

// async global->LDS, 16B per lane (m97 staging path).
__device__ inline void gld_lds16(const void* g, void* l) {
    __builtin_amdgcn_global_load_lds(
        (const __attribute__((address_space(1))) unsigned int*)g,
        (__attribute__((address_space(3))) unsigned int*)l, 16, 0, 0);
}

// ---------------------------------------------------------------------------
// KV projection — R10 kernel verbatim (session-best config, 180.9 us total).
// Evidence ledger: 8 kv/qkv structural variants (pass-split, o-halved,
// 8-wave, LDS-coalesced stores, grid-fused w/ sw barrier) ALL regressed or
// failed; the R13 fusion experiment proved the ~70us residual is real
// work + cache-handoff behavior (fusion forces kTs/vS through HBM via
// fences: WRITE_SIZE 17->36MB, MfmaUtil 29->12), NOT launch overhead.
// Keep the two-kernel structure: the kv->attn L2 warm handoff is free.
// kTs bf16 [b][n][o'] o-blocks ^ (n&15). vS bf16 [b][o][n'] 32-key windows,
// block' ^= (o>>1)&3. XCD map b = bid&7.
// mfma_f32_16x16x32_bf16: A[m=l15][k=quad*8+j]; B[k][n=l15];
// C/D row=quad*4+r, col=l15 (end-to-end validated).
// ---------------------------------------------------------------------------
__global__ __launch_bounds__(256) void kv_mfma(
    const float* __restrict__ x,
    const float* __restrict__ Wk, const float* __restrict__ bk,
    const float* __restrict__ Wv, const float* __restrict__ bv,
    unsigned short* __restrict__ kTs, unsigned short* __restrict__ vS)
{
    __shared__ __align__(16) short Xs[64 * 128];    // 16 KB bf16 X^T, swizzled
    __shared__ __align__(16) float Obuf[64 * 132];  // 33.8 KB k-epilogue

    const int t    = threadIdx.x;
    const int w    = t >> 6;
    const int lane = t & 63;
    const int l15  = lane & 15;
    const int quad = lane >> 4;

    const int b  = blockIdx.x & 7;               // XCD-pinned batch
    const int n0 = (blockIdx.x >> 3) * 64;
    const long base = (long)b * C_ * N_;

    auto load_af = [&](const float* __restrict__ W, short8 (&af)[2][4]) {
        #pragma unroll
        for (int ot = 0; ot < 2; ++ot) {
            const int o = 32 * w + 16 * ot + l15;
            #pragma unroll
            for (int ks = 0; ks < 4; ++ks) {
                const float4 a0 = *(const float4*)(const void*)(W + o * C_ + ks * 32 + quad * 8);
                const float4 a1 = *(const float4*)(const void*)(W + o * C_ + ks * 32 + quad * 8 + 4);
                union { unsigned int u[4]; short8 s; } pk;
                asm("v_cvt_pk_bf16_f32 %0, %1, %2" : "=v"(pk.u[0]) : "v"(a0.x), "v"(a0.y));
                asm("v_cvt_pk_bf16_f32 %0, %1, %2" : "=v"(pk.u[1]) : "v"(a0.z), "v"(a0.w));
                asm("v_cvt_pk_bf16_f32 %0, %1, %2" : "=v"(pk.u[2]) : "v"(a1.x), "v"(a1.y));
                asm("v_cvt_pk_bf16_f32 %0, %1, %2" : "=v"(pk.u[3]) : "v"(a1.z), "v"(a1.w));
                af[ot][ks] = pk.s;
            }
        }
    };

    auto mfma_pass = [&](const short8 (&af)[2][4], f32x4 (&acc)[2][4]) {
        #pragma unroll
        for (int ot = 0; ot < 2; ++ot)
            #pragma unroll
            for (int nt = 0; nt < 4; ++nt)
                acc[ot][nt] = (f32x4){0.f, 0.f, 0.f, 0.f};
        #pragma unroll
        for (int nt = 0; nt < 4; ++nt) {
            const int n = nt * 16 + l15;
            short8 bx[4];
            #pragma unroll
            for (int ks = 0; ks < 4; ++ks)
                bx[ks] = *(const short8*)(const void*)(Xs + n * 128 + (((ks * 4 + quad) ^ l15) << 3));
            #pragma unroll
            for (int ot = 0; ot < 2; ++ot)
                #pragma unroll
                for (int ks = 0; ks < 4; ++ks)
                    acc[ot][nt] = __builtin_amdgcn_mfma_f32_16x16x32_bf16(af[ot][ks], bx[ks], acc[ot][nt], 0, 0, 0);
        }
    };

    // ---- W(v) A-frags first, then stage X^T tile ----
    short8 afA[2][4], afB[2][4];
    load_af(Wv, afA);

    #pragma unroll
    for (int it = 0; it < 8; ++it) {
        const int c  = (t >> 4) + it * 16;
        const int n4 = (t & 15) * 4;
        const float4 xv = *(const float4*)(const void*)(x + base + (long)c * N_ + n0 + n4);
        const int bc = c >> 3, cl = c & 7;
        Xs[(n4 + 0) * 128 + ((bc ^ ((n4 + 0) & 15)) << 3) + cl] = (short)f2b(xv.x);
        Xs[(n4 + 1) * 128 + ((bc ^ ((n4 + 1) & 15)) << 3) + cl] = (short)f2b(xv.y);
        Xs[(n4 + 2) * 128 + ((bc ^ ((n4 + 2) & 15)) << 3) + cl] = (short)f2b(xv.z);
        Xs[(n4 + 3) * 128 + ((bc ^ ((n4 + 3) & 15)) << 3) + cl] = (short)f2b(xv.w);
    }
    __syncthreads();

    { // ======== pass 1: v -> vS bf16, direct swizzled store (R8 form) ========
        load_af(Wk, afB);                          // prefetch k weights
        f32x4 acc[2][4];
        mfma_pass(afA, acc);
        #pragma unroll
        for (int ot = 0; ot < 2; ++ot)
            #pragma unroll
            for (int r = 0; r < 4; ++r) {
                const int o = 32 * w + 16 * ot + quad * 4 + r;
                const float bb = bv[o];
                const int sw = ((o >> 1) & 3) << 3;
                #pragma unroll
                for (int nt = 0; nt < 4; ++nt) {
                    const int n = nt * 16 + l15;
                    const int ns = (n & 32) | ((((n >> 3) & 3) << 3) ^ sw) | (n & 7);
                    vS[base + (long)o * N_ + n0 + ns] = f2b(acc[ot][nt][r] + bb);
                }
            }
    }

    { // ======== pass 2: k -> kTs bf16 [b][n][o'] via Obuf (stride 132) ========
        f32x4 acc[2][4];
        mfma_pass(afB, acc);
        #pragma unroll
        for (int ot = 0; ot < 2; ++ot)
            #pragma unroll
            for (int r = 0; r < 4; ++r) {
                const int o = 32 * w + 16 * ot + quad * 4 + r;
                const float bb = bk[o];
                #pragma unroll
                for (int nt = 0; nt < 4; ++nt) {
                    const int n = nt * 16 + l15;
                    Obuf[n * 132 + (((o >> 3) ^ l15) << 3) + (o & 7)] = acc[ot][nt][r] + bb;
                }
            }
        __syncthreads();
        const int n = t >> 2, oh = (t & 3) * 32;
        #pragma unroll
        for (int i = 0; i < 32; i += 8) {
            const float4 k0 = *(const float4*)(const void*)(Obuf + n * 132 + oh + i);
            const float4 k1 = *(const float4*)(const void*)(Obuf + n * 132 + oh + i + 4);
            union { unsigned int u[4]; short8 s; } pk;
            asm("v_cvt_pk_bf16_f32 %0, %1, %2" : "=v"(pk.u[0]) : "v"(k0.x), "v"(k0.y));
            asm("v_cvt_pk_bf16_f32 %0, %1, %2" : "=v"(pk.u[1]) : "v"(k0.z), "v"(k0.w));
            asm("v_cvt_pk_bf16_f32 %0, %1, %2" : "=v"(pk.u[2]) : "v"(k1.x), "v"(k1.y));
            asm("v_cvt_pk_bf16_f32 %0, %1, %2" : "=v"(pk.u[3]) : "v"(k1.z), "v"(k1.w));
            *(short8*)(void*)(kTs + base + (long)(n0 + n) * C_ + oh + i) = pk.s;
        }
    }
}

// ---------------------------------------------------------------------------
// MFMA flash attention + residual — R10 kernel verbatim (108.3 us, passed,
// absmax bit-exact). Q computed in-block (preamble on staged X tile), main
// loop = R3/R8/R9-proven structure: K global->reg prefetch, single
// barrier/iter (vmcnt(4)+lgkmcnt(0)), P parity-dbuf, V gld_lds16 dbuf,
// b128 V reads, cvt_pk bf16, setprio on MFMA clusters.
// ---------------------------------------------------------------------------
__global__ __launch_bounds__(512, 4) void attn_mfma(
    const float* __restrict__ Wq, const float* __restrict__ bq,
    const unsigned short* __restrict__ kTs,
    const unsigned short* __restrict__ vS,
    const float* __restrict__ xg,
    float* out)
{
    __shared__ union {
        struct {
            short V[2][2][4096];         // [buf][grp][128 ch x 32 keys] swizzled
            short Pb[2][2][2][32 * 40];  // [iter-parity][grp][wq] 32q x 32k
        } s;
        struct {
            short Xst[64 * 128];         // preamble: X^T swizzled (= V[0] bytes)
            short Qs[64 * 128];          // preamble: Q^T swizzled (= V[1] bytes)
        } pre;
        float Ot[64 * 130];              // epilogue merge buffer
    } sm;
    __shared__ float Ls[2][2][32];       // [g][wq][row32] row-sums
    __shared__ float linvA[64];

    const int t    = threadIdx.x;
    const int w    = t >> 6;          // 0..7
    const int g    = w >> 2;          // key-group (2048-key half)
    const int wq   = (w >> 1) & 1;    // 32-query subtile
    const int h    = w & 1;           // QK: key-half; PV: channel-half
    const int sub  = w & 3;           // staging sub-tile
    const int lane = t & 63;
    const int l15  = lane & 15;
    const int quad = lane >> 4;

    const int b  = blockIdx.x & 7;               // XCD-pinned batch
    const int n0 = (blockIdx.x >> 3) * 64;
    const long base = (long)b * C_ * N_;

    // ================= preamble: compute Q tile in LDS =================
    #pragma unroll
    for (int it = 0; it < 4; ++it) {             // 512 threads: 4 float4 each
        const int c  = (t >> 4) + it * 32;
        const int n4 = (t & 15) * 4;
        const float4 xv = *(const float4*)(const void*)(xg + base + (long)c * N_ + n0 + n4);
        const int bc = c >> 3, cl = c & 7;
        sm.pre.Xst[(n4 + 0) * 128 + ((bc ^ ((n4 + 0) & 15)) << 3) + cl] = (short)f2b(xv.x);
        sm.pre.Xst[(n4 + 1) * 128 + ((bc ^ ((n4 + 1) & 15)) << 3) + cl] = (short)f2b(xv.y);
        sm.pre.Xst[(n4 + 2) * 128 + ((bc ^ ((n4 + 2) & 15)) << 3) + cl] = (short)f2b(xv.z);
        sm.pre.Xst[(n4 + 3) * 128 + ((bc ^ ((n4 + 3) & 15)) << 3) + cl] = (short)f2b(xv.w);
    }
    __syncthreads();
    {   // per-wave: 16 o-rows of Wq; 16 MFMA; scatter (acc+bq)*SCALE as bf16
        short8 aq[4];
        const int o = 16 * w + l15;
        #pragma unroll
        for (int ks = 0; ks < 4; ++ks) {
            const float4 a0 = *(const float4*)(const void*)(Wq + o * C_ + ks * 32 + quad * 8);
            const float4 a1 = *(const float4*)(const void*)(Wq + o * C_ + ks * 32 + quad * 8 + 4);
            union { unsigned int u[4]; short8 s; } pk;
            asm("v_cvt_pk_bf16_f32 %0, %1, %2" : "=v"(pk.u[0]) : "v"(a0.x), "v"(a0.y));
            asm("v_cvt_pk_bf16_f32 %0, %1, %2" : "=v"(pk.u[1]) : "v"(a0.z), "v"(a0.w));
            asm("v_cvt_pk_bf16_f32 %0, %1, %2" : "=v"(pk.u[2]) : "v"(a1.x), "v"(a1.y));
            asm("v_cvt_pk_bf16_f32 %0, %1, %2" : "=v"(pk.u[3]) : "v"(a1.z), "v"(a1.w));
            aq[ks] = pk.s;
        }
        f32x4 qa[4];
        #pragma unroll
        for (int nt = 0; nt < 4; ++nt) qa[nt] = (f32x4){0.f, 0.f, 0.f, 0.f};
        #pragma unroll
        for (int nt = 0; nt < 4; ++nt) {
            const int n = nt * 16 + l15;
            #pragma unroll
            for (int ks = 0; ks < 4; ++ks) {
                const short8 bx = *(const short8*)(const void*)(
                    sm.pre.Xst + n * 128 + (((ks * 4 + quad) ^ l15) << 3));
                qa[nt] = __builtin_amdgcn_mfma_f32_16x16x32_bf16(aq[ks], bx, qa[nt], 0, 0, 0);
            }
        }
        const float4 bb = *(const float4*)(const void*)(bq + 16 * w + quad * 4);
        #pragma unroll
        for (int r = 0; r < 4; ++r) {
            const int oo = 16 * w + quad * 4 + r;
            const float br = r == 0 ? bb.x : r == 1 ? bb.y : r == 2 ? bb.z : bb.w;
            #pragma unroll
            for (int nt = 0; nt < 4; ++nt) {
                const int n = nt * 16 + l15;
                sm.pre.Qs[n * 128 + (((oo >> 3) ^ (n & 15)) << 3) + (oo & 7)] =
                    (short)f2b((qa[nt][r] + br) * SCALE);
            }
        }
    }
    __syncthreads();

    // ---- Q B-frags from Qs (verbatim bx pattern; bit-identical to old q) ----
    short8 qf[2][4];
    #pragma unroll
    for (int qh = 0; qh < 2; ++qh)
        #pragma unroll
        for (int ks = 0; ks < 4; ++ks) {
            const int query = 32 * wq + qh * 16 + l15;   // local row, &15 == l15
            qf[qh][ks] = *(const short8*)(const void*)(
                sm.pre.Qs + query * 128 + (((ks * 4 + quad) ^ l15) << 3));
        }

    f32x4 acc[2][4];                  // [qh][ct]: 32q x 64c (channel-half h)
    #pragma unroll
    for (int qh = 0; qh < 2; ++qh)
        #pragma unroll
        for (int ct = 0; ct < 4; ++ct) acc[qh][ct] = (f32x4){0.f, 0.f, 0.f, 0.f};
    f32x4 accS[2];
    accS[0] = (f32x4){0.f, 0.f, 0.f, 0.f};
    accS[1] = (f32x4){0.f, 0.f, 0.f, 0.f};
    short8 ones;
    #pragma unroll
    for (int j = 0; j < 8; ++j) ones[j] = (short)0x3F80;   // bf16 1.0

    auto stageV = [&](int buf, int pair) {       // exactly 2 VMEM ops / lane
        const int mt = pair * 2 + g;
        char* lV = (char*)sm.s.V[buf][g];
        #pragma unroll
        for (int jj = 0; jj < 2; ++jj) {
            const int d  = sub * 2048 + jj * 1024;
            const int dv = d + lane * 16;
            const int c  = dv >> 6;
            gld_lds16((const char*)(vS + base + (long)c * N_ + mt * 32) + (dv & 63), lV + d);
        }
    };

    // ---- K direct global->reg: key = mt*32 + h*16 + l15, key&15 == l15 so
    // the baked-in kTs swizzle inverts with the same XOR as the LDS path ----
    const unsigned short* kp = kTs + base + (long)((g * 32 + h * 16 + l15) * C_);
    int ko[4];
    #pragma unroll
    for (int ks = 0; ks < 4; ++ks) ko[ks] = (((ks * 4 + quad) ^ l15) << 3);
    short8 kf[4];

    stageV(0, 0);
    #pragma unroll
    for (int ks = 0; ks < 4; ++ks) kf[ks] = *(const short8*)(const void*)(kp + ko[ks]);
    kp += 64 * C_;

    for (int i = 0; i < 64; ++i) {
        // ---- QK phase (registers only): P[32q][16k(h)] ----
        f32x4 sc[2];
        sc[0] = (f32x4){0.f, 0.f, 0.f, 0.f};
        sc[1] = (f32x4){0.f, 0.f, 0.f, 0.f};
        __builtin_amdgcn_s_setprio(1);
        #pragma unroll
        for (int qh = 0; qh < 2; ++qh)
            #pragma unroll
            for (int ks = 0; ks < 4; ++ks)
                sc[qh] = __builtin_amdgcn_mfma_f32_16x16x32_bf16(qf[qh][ks], kf[ks], sc[qh], 0, 0, 0);
        __builtin_amdgcn_s_setprio(0);

        // ---- prefetch kf(i+1): regs free, ~full iteration in flight ----
        if (i < 63) {
            #pragma unroll
            for (int ks = 0; ks < 4; ++ks) kf[ks] = *(const short8*)(const void*)(kp + ko[ks]);
            kp += 64 * C_;
        }

        // ---- softmax numerator -> P (iter-parity double buffer) ----
        short* Pw = sm.s.Pb[i & 1][g][wq];
        #pragma unroll
        for (int qh = 0; qh < 2; ++qh)
            #pragma unroll
            for (int r = 0; r < 4; ++r)
                Pw[(qh * 16 + quad * 4 + r) * 40 + h * 16 + l15] = (short)f2b(__expf(sc[qh][r]));

        // ---- single sync point: V(i) staged (vmcnt: kf(i+1) stays in
        // flight), own P writes drained, then barrier ----
        if (i < 63) asm volatile("s_waitcnt vmcnt(4)" ::: "memory");
        else        asm volatile("s_waitcnt vmcnt(0)" ::: "memory");
        asm volatile("s_waitcnt lgkmcnt(0)" ::: "memory");
        __builtin_amdgcn_s_barrier();
        __builtin_amdgcn_sched_barrier(0);

        // ---- V(i+1) stage: earliest legal point (all PV(i-1) reads of this
        // buffer completed before anyone passed B(i)) ----
        if (i < 63) stageV((i + 1) & 1, i + 1);

        // ---- PV phase: channel-half h, full 32-key P ----
        const short* Vb = sm.s.V[i & 1][g];
        const short8 pf0 = *(const short8*)(const void*)(Pw + (l15) * 40 + quad * 8);
        const short8 pf1 = *(const short8*)(const void*)(Pw + (16 + l15) * 40 + quad * 8);
        __builtin_amdgcn_s_setprio(1);
        if (h == 0) {                          // row-sums once per (g,wq)
            accS[0] = __builtin_amdgcn_mfma_f32_16x16x32_bf16(pf0, ones, accS[0], 0, 0, 0);
            accS[1] = __builtin_amdgcn_mfma_f32_16x16x32_bf16(pf1, ones, accS[1], 0, 0, 0);
        }
        #pragma unroll
        for (int ct = 0; ct < 4; ++ct) {
            const int ch = h * 64 + ct * 16 + l15;
            const short8 vf = *(const short8*)(const void*)(Vb + ch * 32 + ((quad ^ ((l15 >> 1) & 3)) << 3));
            acc[0][ct] = __builtin_amdgcn_mfma_f32_16x16x32_bf16(pf0, vf, acc[0][ct], 0, 0, 0);
            acc[1][ct] = __builtin_amdgcn_mfma_f32_16x16x32_bf16(pf1, vf, acc[1][ct], 0, 0, 0);
        }
        __builtin_amdgcn_s_setprio(0);
    }

    // ---- merge epilogue: Ot = O_g0 + O_g1; l via Ls; normalize + residual ----
    if (h == 0 && l15 == 0) {
        #pragma unroll
        for (int qh = 0; qh < 2; ++qh)
            #pragma unroll
            for (int r = 0; r < 4; ++r)
                Ls[g][wq][qh * 16 + quad * 4 + r] = accS[qh][r];
    }
    __syncthreads();                  // all PV reads done before Ot overlays LDS
    if (g == 0) {
        #pragma unroll
        for (int qh = 0; qh < 2; ++qh)
            #pragma unroll
            for (int ct = 0; ct < 4; ++ct)
                #pragma unroll
                for (int r = 0; r < 4; ++r)
                    sm.Ot[(32 * wq + qh * 16 + quad * 4 + r) * 130 + h * 64 + ct * 16 + l15] = acc[qh][ct][r];
    }
    __syncthreads();
    if (g == 1) {
        #pragma unroll
        for (int qh = 0; qh < 2; ++qh)
            #pragma unroll
            for (int ct = 0; ct < 4; ++ct)
                #pragma unroll
                for (int r = 0; r < 4; ++r)
                    sm.Ot[(32 * wq + qh * 16 + quad * 4 + r) * 130 + h * 64 + ct * 16 + l15] += acc[qh][ct][r];
    } else if (h == 0 && l15 == 0) {
        #pragma unroll
        for (int qh = 0; qh < 2; ++qh)
            #pragma unroll
            for (int r = 0; r < 4; ++r) {
                const int r32 = qh * 16 + quad * 4 + r;
                linvA[32 * wq + r32] = 1.0f / fmaxf(Ls[0][wq][r32] + Ls[1][wq][r32], 1e-20f);
            }
    }
    __syncthreads();

    const int c  = t >> 2;
    const int nh = (t & 3) * 16;
    const long gb = base + (long)c * N_ + n0 + nh;
    #pragma unroll
    for (int i = 0; i < 16; i += 4) {
        const float4 xs = *(const float4*)(const void*)(xg + gb + i);
        float4 rv;
        rv.x = sm.Ot[(nh + i + 0) * 130 + c] * linvA[nh + i + 0] + xs.x;
        rv.y = sm.Ot[(nh + i + 1) * 130 + c] * linvA[nh + i + 1] + xs.y;
        rv.z = sm.Ot[(nh + i + 2) * 130 + c] * linvA[nh + i + 2] + xs.z;
        rv.w = sm.Ot[(nh + i + 3) * 130 + c] * linvA[nh + i + 3] + xs.w;
        *(float4*)(void*)(out + gb + i) = rv;
    }
}

// ---------------------------------------------------------------------------
extern "C" void kernel_launch(void* const* d_in, const int* in_sizes, int n_in,
                              void* d_out, int out_size, void* d_ws, size_t ws_size,
                              hipStream_t stream) {
    const float* x  = (const float*)d_in[0];
    const float* Wq = (const float*)d_in[1];
    const float* bq = (const float*)d_in[2];
    const float* Wk = (const float*)d_in[3];
    const float* bk = (const float*)d_in[4];
    const float* Wv = (const float*)d_in[5];
    const float* bv = (const float*)d_in[6];
    float* out = (float*)d_out;

    const long BCN = (long)B_ * C_ * N_;                  // 4,194,304
    unsigned short* kTs = (unsigned short*)d_ws;          // [b][n][o'] bf16 swizzled
    unsigned short* vS  = kTs + BCN;                      // [b][o][n'] bf16 swizzled

    kv_mfma<<<512, 256, 0, stream>>>(x, Wk, bk, Wv, bv, kTs, vS);
    attn_mfma<<<B_ * (N_ / 64), 512, 0, stream>>>(Wq, bq, kTs, vS, x, out);
}